// Round 3
// baseline (50.494 us; speedup 1.0000x reference)
//
#include <hip/hip_runtime.h>

// YOLOv2 loss, single fused kernel, gated+coalesced pred gather.
// preds [B,S,S,A,25] f32, labels [B,S,S,25] f32, out scalar f32.
constexpr int kB     = 1024;
constexpr int kS     = 13;
constexpr int kA     = 5;
constexpr int kC5    = 25;
constexpr int kRec   = kA * kC5;          // 125 floats per cell's pred record
constexpr int kCells = kB * kS * kS;      // 173056
constexpr int kBlock = 256;
constexpr int kCPB   = 64;                // cells per block
constexpr int kNBlk  = kCells / kCPB;     // 2704 (exact)
constexpr int kChunk = 32;                // obj records gathered per pass
constexpr int kPadRec = kRec + 1;         // 126: LDS record stride
static_assert(kCells % kCPB == 0, "grid must tile exactly");

__global__ __launch_bounds__(kBlock)
void yolo_v3(const float* __restrict__ preds,
             const float* __restrict__ labels,
             float* __restrict__ out)
{
    __shared__ float lab[kCPB * kC5];              // 6400 B
    __shared__ float pbox[kChunk * kPadRec];       // 16128 B
    __shared__ unsigned short objIdx[kCPB];
    __shared__ int nObjS;

    const int tid = threadIdx.x;
    const size_t cellBase = (size_t)blockIdx.x * kCPB;

    // ---- 1) stage 64 cells' labels, coalesced float4 (6400 B, 16B-aligned) ----
    {
        const float4* __restrict__ src = (const float4*)(labels + cellBase * kC5);
        float4* dst = (float4*)lab;
        dst[tid] = src[tid];                                   // 0..255
        if (tid < (kCPB * kC5 / 4) - kBlock)                   // 400-256 = 144
            dst[tid + kBlock] = src[tid + kBlock];
    }
    __syncthreads();

    // ---- 2) compact object cells (wave 0 covers all 64 cells) ----
    const bool isObj = (tid < kCPB) && (lab[tid * kC5 + 4] == 1.0f);
    const unsigned long long m = __ballot(isObj);
    if (tid < kCPB) {
        if (isObj) {
            int pre = __popcll(m & ((1ull << tid) - 1ull));
            objIdx[pre] = (unsigned short)tid;
        }
        if (tid == 0) nObjS = __popcll(m);
    }
    __syncthreads();
    const int nObj = nObjS;

    // ---- 3) chunked: gather full 500B records contiguously, then compute ----
    float loss = 0.0f;
    const float* __restrict__ pb = preds + cellBase * kRec;

    for (int c0 = 0; c0 < nObj; c0 += kChunk) {
        const int mrec = min(nObj - c0, kChunk);

        // cooperative gather: consecutive threads -> consecutive dwords of a
        // record -> fully coalesced 256B wave transactions
        for (int idx = tid; idx < mrec * kRec; idx += kBlock) {
            int k = idx / kRec;            // const-div (magic mul)
            int f = idx - k * kRec;
            pbox[k * kPadRec + f] = pb[(int)objIdx[c0 + k] * kRec + f];
        }
        __syncthreads();

        if (tid < mrec) {
            const int lc = objIdx[c0 + tid];
            const float* __restrict__ L = lab + lc * kC5;
            const float* __restrict__ P = pbox + tid * kPadRec;  // [a*25 + j]

            const float lx = L[0], ly = L[1], lw = L[2], lh = L[3];
            const float lx1 = lx - lw * 0.5f, lx2 = lx + lw * 0.5f;
            const float ly1 = ly - lh * 0.5f, ly2 = ly + lh * 0.5f;
            const float larea = lw * lh;

            float iou[kA], conf[kA];
            int best = 0;
            float bestIou = -1.0f;
            #pragma unroll
            for (int a = 0; a < kA; ++a) {
                const float px = P[a * kC5 + 0], py = P[a * kC5 + 1];
                const float pw = P[a * kC5 + 2], ph = P[a * kC5 + 3];
                conf[a] = P[a * kC5 + 4];
                float px1 = px - pw * 0.5f, px2 = px + pw * 0.5f;
                float py1 = py - ph * 0.5f, py2 = py + ph * 0.5f;
                float iw = fmaxf(fminf(px2, lx2) - fmaxf(px1, lx1), 0.0f);
                float ih = fmaxf(fminf(py2, ly2) - fmaxf(py1, ly1), 0.0f);
                float inter = iw * ih;
                float uni = pw * ph + larea - inter;
                float v = inter / (uni + 1e-12f);
                iou[a] = v;
                if (v > bestIou) { bestIou = v; best = a; }  // strict > == jnp.argmax
            }

            const float* __restrict__ BP = P + best * kC5;
            // xy
            float dx = lx - BP[0], dy = ly - BP[1];
            loss += 5.0f * (dx * dx + dy * dy);
            // wh
            float sw = sqrtf(lw) - sqrtf(BP[2]);
            float sh = sqrtf(lh) - sqrtf(BP[3]);
            loss += sw * sw + sh * sh;
            // obj
            float dob = bestIou - BP[4];
            loss += dob * dob;
            // cls (classes are in the gathered record)
            float cls = 0.0f;
            #pragma unroll
            for (int c = 5; c < kC5; ++c) {
                float d = L[c] - BP[c];
                cls += d * d;
            }
            loss += cls;
            // noobj
            #pragma unroll
            for (int a = 0; a < kA; ++a) {
                if (a != best && iou[a] < 0.6f) {
                    float d = iou[a] - conf[a];
                    loss += d * d;
                }
            }
        }
        __syncthreads();   // protect pbox before next chunk overwrites
    }

    // ---- 4) reduce: loss nonzero only in wave 0 -> shuffle + 1 atomic ----
    if (tid < 64) {
        #pragma unroll
        for (int off = 32; off > 0; off >>= 1)
            loss += __shfl_down(loss, off, 64);
        if (tid == 0 && loss != 0.0f)
            atomicAdd(out, loss * (1.0f / (float)kB));
    }
}

extern "C" void kernel_launch(void* const* d_in, const int* in_sizes, int n_in,
                              void* d_out, int out_size, void* d_ws, size_t ws_size,
                              hipStream_t stream) {
    const float* preds  = (const float*)d_in[0];
    const float* labels = (const float*)d_in[1];
    float* out = (float*)d_out;

    // out is poisoned once and not re-poisoned between replays: zero it
    // every call (async memset is graph-capture legal).
    hipMemsetAsync(out, 0, sizeof(float), stream);
    yolo_v3<<<kNBlk, kBlock, 0, stream>>>(preds, labels, out);
}

// Round 4
// 18.452 us; speedup vs baseline: 2.7365x; 2.7365x over previous
//
#include <hip/hip_runtime.h>

// YOLOv2 loss. preds [B,S,S,A,25] f32, labels [B,S,S,25] f32, out scalar f32.
// Layout: 5 lanes per cell (one per anchor), 12 cells per wave64, no LDS,
// no barriers, no atomics. Per-wave partial sums -> global -> tiny reduce.
constexpr int kB     = 1024;
constexpr int kS     = 13;
constexpr int kA     = 5;
constexpr int kC5    = 25;
constexpr int kRec   = kA * kC5;            // 125 floats per cell pred record
constexpr int kCells = kB * kS * kS;        // 173056
constexpr int kBlock = 256;                 // 4 waves
constexpr int kCPW   = 12;                  // cells per wave (5 lanes each, 4 idle)
constexpr int kCPB   = kCPW * 4;            // 48 cells per block
constexpr int kNBlk  = (kCells + kCPB - 1) / kCPB;   // 3606
constexpr int kNWave = kNBlk * 4;           // 14424 wave partials

__global__ __launch_bounds__(kBlock)
void yolo_main(const float* __restrict__ preds,
               const float* __restrict__ labels,
               float* __restrict__ partial)
{
    const int tid   = threadIdx.x;
    const int lane  = tid & 63;
    const int wid   = tid >> 6;
    const int c     = lane / 5;                   // 0..12 (12 -> idle lane)
    const int a     = lane - c * 5;               // anchor 0..4
    const int gbase = c * 5;                      // group's first lane

    const int cell  = blockIdx.x * kCPB + wid * kCPW + c;
    const bool valid = (c < kCPW) && (cell < kCells);

    float loss = 0.0f;

    // gate: objectness (group-uniform; 5 lanes read same address -> 1 req/line)
    float objc = 0.0f;
    if (valid) objc = labels[(size_t)cell * kC5 + 4];

    if (valid && objc == 1.0f) {
        const float* __restrict__ L = labels + (size_t)cell * kC5;
        const float* __restrict__ P = preds + (size_t)cell * kRec + a * kC5;

        // own anchor's box+conf (5 scalar loads; group spans its record's lines)
        const float px = P[0], py = P[1], pw = P[2], ph = P[3], pc = P[4];
        // label box (uniform within group)
        const float lx = L[0], ly = L[1], lw = L[2], lh = L[3];

        // IoU of own anchor vs label
        const float lx1 = lx - lw * 0.5f, lx2 = lx + lw * 0.5f;
        const float ly1 = ly - lh * 0.5f, ly2 = ly + lh * 0.5f;
        const float px1 = px - pw * 0.5f, px2 = px + pw * 0.5f;
        const float py1 = py - ph * 0.5f, py2 = py + ph * 0.5f;
        const float iw = fmaxf(fminf(px2, lx2) - fmaxf(px1, lx1), 0.0f);
        const float ih = fmaxf(fminf(py2, ly2) - fmaxf(py1, ly1), 0.0f);
        const float inter = iw * ih;
        const float uni = pw * ph + lw * lh - inter;
        const float iou = inter / (uni + 1e-12f);

        // group argmax (ascending j + strict > == jnp.argmax first-max).
        // All 5 lanes of the group are in this branch together -> shfl sources
        // are active; result is group-uniform.
        int best = 0;
        float bestIou = -1.0f;
        #pragma unroll
        for (int j = 0; j < kA; ++j) {
            float v = __shfl(iou, gbase + j, 64);
            if (v > bestIou) { bestIou = v; best = j; }
        }

        if (a == best) {
            // xy (box already in registers on this lane)
            const float dx = lx - px, dy = ly - py;
            loss += 5.0f * (dx * dx + dy * dy);
            // wh
            const float sw = sqrtf(lw) - sqrtf(pw);
            const float sh = sqrtf(lh) - sqrtf(ph);
            loss += sw * sw + sh * sh;
            // obj
            const float dob = bestIou - pc;
            loss += dob * dob;
        } else if (iou < 0.6f) {
            // noobj for own (non-best) anchor
            const float d = iou - pc;
            loss += d * d;
        }

        // classes: 20 terms split 4 per lane; group covers j = 5..24
        const float* __restrict__ BP = preds + (size_t)cell * kRec + best * kC5;
        #pragma unroll
        for (int r = 0; r < 4; ++r) {
            const int j = 5 + r * 5 + a;
            const float d = L[j] - BP[j];
            loss += d * d;
        }
    }

    // wave reduction -> one partial per wave (no LDS, no atomics)
    #pragma unroll
    for (int off = 32; off > 0; off >>= 1)
        loss += __shfl_down(loss, off, 64);
    if (lane == 0)
        partial[blockIdx.x * 4 + wid] = loss;
}

__global__ __launch_bounds__(1024)
void yolo_reduce(const float* __restrict__ partial, float* __restrict__ out)
{
    float s = 0.0f;
    for (int i = threadIdx.x; i < kNWave; i += 1024)
        s += partial[i];
    #pragma unroll
    for (int off = 32; off > 0; off >>= 1)
        s += __shfl_down(s, off, 64);
    __shared__ float sred[16];
    const int lane = threadIdx.x & 63;
    const int wid  = threadIdx.x >> 6;
    if (lane == 0) sred[wid] = s;
    __syncthreads();
    if (threadIdx.x == 0) {
        float t = 0.0f;
        #pragma unroll
        for (int w = 0; w < 16; ++w) t += sred[w];
        out[0] = t * (1.0f / (float)kB);
    }
}

extern "C" void kernel_launch(void* const* d_in, const int* in_sizes, int n_in,
                              void* d_out, int out_size, void* d_ws, size_t ws_size,
                              hipStream_t stream) {
    const float* preds  = (const float*)d_in[0];
    const float* labels = (const float*)d_in[1];
    float* out     = (float*)d_out;
    float* partial = (float*)d_ws;          // kNWave floats = 57.7 KB scratch

    yolo_main<<<kNBlk, kBlock, 0, stream>>>(preds, labels, partial);
    yolo_reduce<<<1, 1024, 0, stream>>>(partial, out);
}